// Round 1
// baseline (926.594 us; speedup 1.0000x reference)
//
#include <hip/hip_runtime.h>
#include <hip/hip_bf16.h>
#include <math.h>

typedef unsigned short ushortT;
typedef __attribute__((ext_vector_type(8))) short short8;
typedef __attribute__((ext_vector_type(4))) short short4v;
typedef __attribute__((ext_vector_type(4))) float f32x4;
typedef __attribute__((ext_vector_type(4))) float float4v;

#define TOK 65536
#define NSEQ 4096
#define DIM 512

__device__ __forceinline__ float bf2f(ushortT u) {
  union { float f; unsigned int i; } v; v.i = ((unsigned int)u) << 16; return v.f;
}
__device__ __forceinline__ ushortT f2bf(float f) {
  union { float f; unsigned int i; } v; v.f = f;
  unsigned int r = v.i + 0x7fffu + ((v.i >> 16) & 1u);
  return (ushortT)(r >> 16);
}

#define GLOAD_LDS(gp, lp) __builtin_amdgcn_global_load_lds( \
    (const __attribute__((address_space(1))) unsigned int*)(gp), \
    (__attribute__((address_space(3))) unsigned int*)(lp), 16, 0, 0)

// ---------------- weight f32 -> bf16 convert ----------------
__global__ void cvt_kernel(const float* __restrict__ in, ushortT* __restrict__ out, int n4) {
  int i = blockIdx.x * 256 + threadIdx.x;
  if (i >= n4) return;
  float4v v = *(const float4v*)(in + (size_t)i * 4);
  short4v o;
#pragma unroll
  for (int j = 0; j < 4; ++j) o[j] = (short)f2bf(v[j]);
  *(short4v*)(out + (size_t)i * 4) = o;
}

// ---------------- LayerNorm (one wave per token) ----------------
template <bool INBF>
__global__ __launch_bounds__(256)
void ln_kernel(const void* __restrict__ inp, const float* __restrict__ gw,
               const float* __restrict__ bw, ushortT* __restrict__ out)
{
  const int lane = threadIdx.x & 63;
  const size_t tok = (size_t)blockIdx.x * 4 + (threadIdx.x >> 6);
  const int col = lane * 8;
  float x[8];
  if constexpr (INBF) {
    short8 v = *(const short8*)((const ushortT*)inp + tok * DIM + col);
#pragma unroll
    for (int j = 0; j < 8; ++j) x[j] = bf2f((ushortT)v[j]);
  } else {
    const float* p = (const float*)inp + tok * DIM + col;
    float4v a = *(const float4v*)p, b = *(const float4v*)(p + 4);
#pragma unroll
    for (int j = 0; j < 4; ++j) { x[j] = a[j]; x[4 + j] = b[j]; }
  }
  float s = 0.f, ss = 0.f;
#pragma unroll
  for (int j = 0; j < 8; ++j) { s += x[j]; ss += x[j] * x[j]; }
#pragma unroll
  for (int off = 1; off < 64; off <<= 1) {
    s += __shfl_xor(s, off, 64);
    ss += __shfl_xor(ss, off, 64);
  }
  const float mean = s * (1.f / 512.f);
  const float var = ss * (1.f / 512.f) - mean * mean;
  const float rstd = rsqrtf(var + 1e-5f);
  float4v g1 = *(const float4v*)(gw + col), g2 = *(const float4v*)(gw + col + 4);
  float4v b1 = *(const float4v*)(bw + col), b2 = *(const float4v*)(bw + col + 4);
  short8 o;
#pragma unroll
  for (int j = 0; j < 4; ++j) {
    o[j]     = (short)f2bf((x[j]     - mean) * rstd * g1[j] + b1[j]);
    o[4 + j] = (short)f2bf((x[4 + j] - mean) * rstd * g2[j] + b2[j]);
  }
  *(short8*)(out + tok * DIM + col) = o;
}

// ---------------- GEMM: C = A(M,K) * Bt(N,K)^T + bias, fused epilogues ----------------
// EPI 0: out bf16         (QKV)
// EPI 1: out bf16, + f32 residual             (proj -> x1)
// EPI 2: out bf16, exact GELU                 (fc1)
// EPI 3: out f32,  + bf16 residual            (fc2 -> d_out)
template <int EPI>
__global__ __launch_bounds__(256)
void gemm_bt(const ushortT* __restrict__ A, const ushortT* __restrict__ Bt,
             const float* __restrict__ bias, int M, int N, int K,
             ushortT* __restrict__ outb, float* __restrict__ outf,
             const float* __restrict__ resf, const ushortT* __restrict__ resb)
{
  __shared__ __align__(16) ushortT As[128 * 32];
  __shared__ __align__(16) ushortT Bs[128 * 32];
  const int tid  = threadIdx.x;
  const int wave = tid >> 6;
  const int lane = tid & 63;
  const int m0 = blockIdx.x * 128;
  const int n0 = blockIdx.y * 128;
  const int wr = (wave >> 1) * 64;
  const int wc = (wave & 1) * 64;
  const int r = lane & 15, q = lane >> 4;

  f32x4 acc[4][4];
  const f32x4 zero = {0.f, 0.f, 0.f, 0.f};
#pragma unroll
  for (int i = 0; i < 4; ++i)
#pragma unroll
    for (int j = 0; j < 4; ++j) acc[i][j] = zero;

  const int c0 = wave * 2;
  const ushortT* Ag = A  + (size_t)(m0 + c0 * 16 + (lane >> 2)) * K + (lane & 3) * 8;
  const ushortT* Bg = Bt + (size_t)(n0 + c0 * 16 + (lane >> 2)) * K + (lane & 3) * 8;
  ushortT* Al0 = As + c0 * 512;  // 1024B chunk per wave-load
  ushortT* Bl0 = Bs + c0 * 512;
  const ushortT* Ard = As + (wr + r) * 32 + q * 8;
  const ushortT* Brd = Bs + (wc + r) * 32 + q * 8;

  for (int kt = 0; kt < K; kt += 32) {
    GLOAD_LDS(Ag + kt,                  Al0);
    GLOAD_LDS(Ag + (size_t)16 * K + kt, Al0 + 512);
    GLOAD_LDS(Bg + kt,                  Bl0);
    GLOAD_LDS(Bg + (size_t)16 * K + kt, Bl0 + 512);
    __syncthreads();
    short8 af[4], bv[4];
#pragma unroll
    for (int m = 0; m < 4; ++m) af[m] = *(const short8*)(Ard + m * 16 * 32);
#pragma unroll
    for (int n = 0; n < 4; ++n) bv[n] = *(const short8*)(Brd + n * 16 * 32);
#pragma unroll
    for (int m = 0; m < 4; ++m)
#pragma unroll
      for (int n = 0; n < 4; ++n)
        acc[m][n] = __builtin_amdgcn_mfma_f32_16x16x32_bf16(af[m], bv[n], acc[m][n], 0, 0, 0);
    __syncthreads();
  }

#pragma unroll
  for (int m = 0; m < 4; ++m) {
#pragma unroll
    for (int n = 0; n < 4; ++n) {
      const int col = n0 + wc + n * 16 + r;
      const float bb = bias[col];
#pragma unroll
      for (int i = 0; i < 4; ++i) {
        const size_t row = (size_t)(m0 + wr + m * 16 + q * 4 + i);
        float v = acc[m][n][i] + bb;
        if constexpr (EPI == 1) v += resf[row * (size_t)N + col];
        if constexpr (EPI == 2) v = 0.5f * v * (1.f + erff(v * 0.70710678118654752f));
        if constexpr (EPI == 3) {
          v += bf2f(resb[row * (size_t)N + col]);
          outf[row * (size_t)N + col] = v;
        } else {
          outb[row * (size_t)N + col] = f2bf(v);
        }
      }
    }
  }
}

// ---------------- windowed attention (one block/window, one wave/head) ----------------
// gather: rolled pos p = 64g + 8i + w  -> qkv row (p+4)&4095
// scatter (repo's non-inverse window_reverse): out row (512i + 64w + g + 4)&4095
__global__ __launch_bounds__(512)
void attn_kernel(const ushortT* __restrict__ qkv, ushortT* __restrict__ out)
{
  __shared__ __align__(16) ushortT sq[8][1544];  // 1536 + 8 pad (bank spread)
  const int wb = blockIdx.x;            // 0..8191
  const int b  = wb >> 9;
  const int rr = wb & 511;
  const int w1 = rr >> 6;
  const int g  = rr & 63;
  const int tid = threadIdx.x;

#pragma unroll
  for (int c = 0; c < 3; ++c) {
    const int f = c * 512 + tid;        // 16B-chunk id, 0..1535
    const int i = f / 192;              // token slot 0..7
    const int col = (f % 192) * 8;
    const int tin = (64 * g + 8 * i + w1 + 4) & (NSEQ - 1);
    const ushortT* src = qkv + ((size_t)b * NSEQ + tin) * 1536 + col;
    *(short8*)(&sq[i][col]) = *(const short8*)src;
  }
  __syncthreads();

  const int wave = tid >> 6, lane = tid & 63;
  const int h = wave;
  const int qi = lane >> 3, kj = lane & 7;

  // QK^T
  float s = 0.f;
  const ushortT* qrow = &sq[qi][h * 64];
  const ushortT* krow = &sq[kj][512 + h * 64];
#pragma unroll
  for (int c = 0; c < 8; ++c) {
    short8 qa = *(const short8*)(qrow + c * 8);
    short8 ka = *(const short8*)(krow + c * 8);
#pragma unroll
    for (int j = 0; j < 8; ++j) s += bf2f((ushortT)qa[j]) * bf2f((ushortT)ka[j]);
  }
  s *= 0.125f;  // HD^-0.5

  // shift mask
  const int pq = 64 * g + 8 * qi + w1;
  const int pk = 64 * g + 8 * kj + w1;
  const int cq = (pq < 4088) ? 0 : (pq < 4092 ? 1 : 2);
  const int ck = (pk < 4088) ? 0 : (pk < 4092 ? 1 : 2);
  if (cq != ck) s -= 100.f;

  // softmax over the 8-lane kj group
  float mx = s;
  mx = fmaxf(mx, __shfl_xor(mx, 1, 64));
  mx = fmaxf(mx, __shfl_xor(mx, 2, 64));
  mx = fmaxf(mx, __shfl_xor(mx, 4, 64));
  const float e = expf(s - mx);
  float sum = e;
  sum += __shfl_xor(sum, 1, 64);
  sum += __shfl_xor(sum, 2, 64);
  sum += __shfl_xor(sum, 4, 64);
  const float p = e / sum;

  // PV: lane -> (qi, dc)
  const int dc = lane & 7;
  float o[8];
#pragma unroll
  for (int j = 0; j < 8; ++j) o[j] = 0.f;
#pragma unroll
  for (int k2 = 0; k2 < 8; ++k2) {
    const float pk2 = __shfl(p, (lane & ~7) + k2, 64);
    short8 va = *(const short8*)(&sq[k2][1024 + h * 64 + dc * 8]);
#pragma unroll
    for (int j = 0; j < 8; ++j) o[j] += pk2 * bf2f((ushortT)va[j]);
  }

  const int tout = (512 * qi + 64 * w1 + g + 4) & (NSEQ - 1);
  short8 ov;
#pragma unroll
  for (int j = 0; j < 8; ++j) ov[j] = (short)f2bf(o[j]);
  *(short8*)(out + ((size_t)b * NSEQ + tout) * DIM + h * 64 + dc * 8) = ov;
}

// ---------------- host ----------------
extern "C" void kernel_launch(void* const* d_in, const int* in_sizes, int n_in,
                              void* d_out, int out_size, void* d_ws, size_t ws_size,
                              hipStream_t stream) {
  const float* x      = (const float*)d_in[0];
  const float* n1g    = (const float*)d_in[1];
  const float* n1b    = (const float*)d_in[2];
  const float* qkv_w  = (const float*)d_in[3];
  const float* qkv_b  = (const float*)d_in[4];
  const float* proj_w = (const float*)d_in[5];
  const float* proj_b = (const float*)d_in[6];
  const float* n2g    = (const float*)d_in[7];
  const float* n2b    = (const float*)d_in[8];
  const float* fc1_w  = (const float*)d_in[9];
  const float* fc1_b  = (const float*)d_in[10];
  const float* fc2_w  = (const float*)d_in[11];
  const float* fc2_b  = (const float*)d_in[12];
  float* out = (float*)d_out;

  size_t off = 0;
  char* ws = (char*)d_ws;
  auto alloc = [&](size_t b) { void* p = ws + off; off += (b + 255) & ~(size_t)255; return p; };

  ushortT* qkvw_b = (ushortT*)alloc((size_t)1536 * 512 * 2);
  ushortT* projw_b = (ushortT*)alloc((size_t)512 * 512 * 2);
  ushortT* fc1w_b = (ushortT*)alloc((size_t)2048 * 512 * 2);
  ushortT* fc2w_b = (ushortT*)alloc((size_t)512 * 2048 * 2);
  ushortT* bufA = (ushortT*)alloc((size_t)TOK * 512 * 2);    // xn -> attnout -> h_in
  ushortT* bufQ = (ushortT*)alloc((size_t)TOK * 1536 * 2);   // qkv ; then x1 (bf16)
  ushortT* x1 = bufQ;

  int nch = 1;
  while (nch < 16) {
    size_t need = (size_t)(TOK / nch) * 2048 * 2;
    if (off + need <= ws_size) break;
    nch <<= 1;
  }
  ushortT* h1 = (ushortT*)(ws + off);

  // weights -> bf16
  cvt_kernel<<<(1536 * 512 / 4 + 255) / 256, 256, 0, stream>>>(qkv_w, qkvw_b, 1536 * 512 / 4);
  cvt_kernel<<<(512 * 512 / 4 + 255) / 256, 256, 0, stream>>>(proj_w, projw_b, 512 * 512 / 4);
  cvt_kernel<<<(2048 * 512 / 4 + 255) / 256, 256, 0, stream>>>(fc1_w, fc1w_b, 2048 * 512 / 4);
  cvt_kernel<<<(512 * 2048 / 4 + 255) / 256, 256, 0, stream>>>(fc2_w, fc2w_b, 512 * 2048 / 4);

  // LN1: x -> xn (bf16)
  ln_kernel<false><<<TOK / 4, 256, 0, stream>>>(x, n1g, n1b, bufA);

  // QKV: (65536,512) x (1536,512)^T
  gemm_bt<0><<<dim3(TOK / 128, 1536 / 128), 256, 0, stream>>>(
      bufA, qkvw_b, qkv_b, TOK, 1536, 512, bufQ, nullptr, nullptr, nullptr);

  // attention: qkv -> attnout (bufA)
  attn_kernel<<<8192, 512, 0, stream>>>(bufQ, bufA);

  // proj + residual(x): -> x1 (bf16, in bufQ)
  gemm_bt<1><<<dim3(TOK / 128, 512 / 128), 256, 0, stream>>>(
      bufA, projw_b, proj_b, TOK, 512, 512, x1, nullptr, x, nullptr);

  // LN2: x1 -> h_in (bufA)
  ln_kernel<true><<<TOK / 4, 256, 0, stream>>>(x1, n2g, n2b, bufA);

  // MLP, token-chunked
  const int tc = TOK / nch;
  for (int c = 0; c < nch; ++c) {
    const ushortT* hin = bufA + (size_t)c * tc * 512;
    gemm_bt<2><<<dim3(tc / 128, 2048 / 128), 256, 0, stream>>>(
        hin, fc1w_b, fc1_b, tc, 2048, 512, h1, nullptr, nullptr, nullptr);
    gemm_bt<3><<<dim3(tc / 128, 512 / 128), 256, 0, stream>>>(
        h1, fc2w_b, fc2_b, tc, 512, 2048, nullptr, out + (size_t)c * tc * 512,
        nullptr, x1 + (size_t)c * tc * 512);
  }
}

// Round 2
// 833.719 us; speedup vs baseline: 1.1114x; 1.1114x over previous
//
#include <hip/hip_runtime.h>
#include <hip/hip_bf16.h>
#include <math.h>

typedef unsigned short ushortT;
typedef __attribute__((ext_vector_type(8))) short short8;
typedef __attribute__((ext_vector_type(4))) short short4v;
typedef __attribute__((ext_vector_type(4))) float f32x4;
typedef __attribute__((ext_vector_type(4))) float float4v;

#define TOK 65536
#define NSEQ 4096
#define DIM 512

__device__ __forceinline__ float bf2f(ushortT u) {
  union { float f; unsigned int i; } v; v.i = ((unsigned int)u) << 16; return v.f;
}
__device__ __forceinline__ ushortT f2bf(float f) {
  union { float f; unsigned int i; } v; v.f = f;
  unsigned int r = v.i + 0x7fffu + ((v.i >> 16) & 1u);
  return (ushortT)(r >> 16);
}

#define GLOAD_LDS(gp, lp) __builtin_amdgcn_global_load_lds( \
    (const __attribute__((address_space(1))) unsigned int*)(gp), \
    (__attribute__((address_space(3))) unsigned int*)(lp), 16, 0, 0)

#define LGKM0 do { asm volatile("s_waitcnt lgkmcnt(0)" ::: "memory"); \
                   __builtin_amdgcn_sched_barrier(0); } while (0)
#define BAR __builtin_amdgcn_s_barrier()
#define VMC(n) asm volatile("s_waitcnt vmcnt(" #n ")" ::: "memory")

// ---------------- weight f32 -> bf16 convert ----------------
__global__ void cvt_kernel(const float* __restrict__ in, ushortT* __restrict__ out, int n4) {
  int i = blockIdx.x * 256 + threadIdx.x;
  if (i >= n4) return;
  float4v v = *(const float4v*)(in + (size_t)i * 4);
  short4v o;
#pragma unroll
  for (int j = 0; j < 4; ++j) o[j] = (short)f2bf(v[j]);
  *(short4v*)(out + (size_t)i * 4) = o;
}

// ---------------- LayerNorm (one wave per token) ----------------
template <bool INBF>
__global__ __launch_bounds__(256)
void ln_kernel(const void* __restrict__ inp, const float* __restrict__ gw,
               const float* __restrict__ bw, ushortT* __restrict__ out)
{
  const int lane = threadIdx.x & 63;
  const size_t tok = (size_t)blockIdx.x * 4 + (threadIdx.x >> 6);
  const int col = lane * 8;
  float x[8];
  if constexpr (INBF) {
    short8 v = *(const short8*)((const ushortT*)inp + tok * DIM + col);
#pragma unroll
    for (int j = 0; j < 8; ++j) x[j] = bf2f((ushortT)v[j]);
  } else {
    const float* p = (const float*)inp + tok * DIM + col;
    float4v a = *(const float4v*)p, b = *(const float4v*)(p + 4);
#pragma unroll
    for (int j = 0; j < 4; ++j) { x[j] = a[j]; x[4 + j] = b[j]; }
  }
  float s = 0.f, ss = 0.f;
#pragma unroll
  for (int j = 0; j < 8; ++j) { s += x[j]; ss += x[j] * x[j]; }
#pragma unroll
  for (int off = 1; off < 64; off <<= 1) {
    s += __shfl_xor(s, off, 64);
    ss += __shfl_xor(ss, off, 64);
  }
  const float mean = s * (1.f / 512.f);
  const float var = ss * (1.f / 512.f) - mean * mean;
  const float rstd = rsqrtf(var + 1e-5f);
  float4v g1 = *(const float4v*)(gw + col), g2 = *(const float4v*)(gw + col + 4);
  float4v b1 = *(const float4v*)(bw + col), b2 = *(const float4v*)(bw + col + 4);
  short8 o;
#pragma unroll
  for (int j = 0; j < 4; ++j) {
    o[j]     = (short)f2bf((x[j]     - mean) * rstd * g1[j] + b1[j]);
    o[4 + j] = (short)f2bf((x[4 + j] - mean) * rstd * g2[j] + b2[j]);
  }
  *(short8*)(out + tok * DIM + col) = o;
}

// ---------------- 256x256 8-phase GEMM: C = A(M,K) * Bt(N,K)^T + bias ----------------
// EPI 0: out bf16 (QKV) | 1: bf16 +f32 residual (proj) | 2: bf16 GELU (fc1) | 3: f32 +bf16 residual (fc2)
// 8 waves (2Mx4N), BK=64, double-buffered 128KiB LDS, chunk^=(row&7) 16B swizzle,
// counted vmcnt (6 = 3 half-tiles * 2 loads in flight), setprio around MFMA.
#define MFMA_PHASE(MQ, NQ) \
  _Pragma("unroll") \
  for (int s_ = 0; s_ < 2; ++s_) \
    _Pragma("unroll") \
    for (int m_ = 0; m_ < 4; ++m_) \
      _Pragma("unroll") \
      for (int n_ = 0; n_ < 2; ++n_) \
        acc[(MQ) * 4 + m_][(NQ) * 2 + n_] = __builtin_amdgcn_mfma_f32_16x16x32_bf16( \
            Af[m_][s_], Bf[NQ][n_][s_], acc[(MQ) * 4 + m_][(NQ) * 2 + n_], 0, 0, 0)

#define STAGE_A(bufp, h, kt) do { \
    GLOAD_LDS(gA + (size_t)((h) * 128) * K + (size_t)(kt) * 64,     (bufp) + (h) * 8192 + w * 1024); \
    GLOAD_LDS(gA + (size_t)((h) * 128 + 8) * K + (size_t)(kt) * 64, (bufp) + (h) * 8192 + w * 1024 + 512); \
  } while (0)
#define STAGE_B(bufp, h, kt) do { \
    GLOAD_LDS(gB + (size_t)((h) * 128) * K + (size_t)(kt) * 64,     (bufp) + (h) * 8192 + w * 1024); \
    GLOAD_LDS(gB + (size_t)((h) * 128 + 8) * K + (size_t)(kt) * 64, (bufp) + (h) * 8192 + w * 1024 + 512); \
  } while (0)

template <int EPI>
__global__ __launch_bounds__(512, 2)
void gemm256(const ushortT* __restrict__ A, const ushortT* __restrict__ Bt,
             const float* __restrict__ bias, int M, int N, int K,
             ushortT* __restrict__ outb, float* __restrict__ outf,
             const float* __restrict__ resf, const ushortT* __restrict__ resb)
{
  __shared__ __align__(16) ushortT sm[65536];   // 128 KiB
  ushortT* const Ab0 = sm;
  ushortT* const Ab1 = sm + 16384;
  ushortT* const Bb0 = sm + 32768;
  ushortT* const Bb1 = sm + 49152;

  const int tid = threadIdx.x;
  const int w = tid >> 6, l = tid & 63;
  const int wr = w >> 2, wc = w & 3;

  // XCD-bijective swizzle; consecutive swizzled ids share the A panel (same mb)
  const int nwg = gridDim.x * gridDim.y;
  int wg = blockIdx.y * gridDim.x + blockIdx.x;
  {
    const int q = nwg >> 3, r8 = nwg & 7;
    const int xc = wg & 7, yc = wg >> 3;
    wg = (xc < r8 ? xc * (q + 1) : r8 * (q + 1) + (xc - r8) * q) + yc;
  }
  const int nbn = N >> 8;
  const int mb = wg / nbn, nb = wg % nbn;
  const int m0 = mb << 8, n0 = nb << 8;
  const int NT = K >> 6;

  // staging source (per-lane, inverse-swizzled chunk)
  const ushortT* gA = A  + (size_t)(m0 + w * 16 + (l >> 3)) * K + (((l & 7) ^ (l >> 3)) << 3);
  const ushortT* gB = Bt + (size_t)(n0 + w * 16 + (l >> 3)) * K + (((l & 7) ^ (l >> 3)) << 3);

  // ds_read addressing (swizzled)
  const int rl = l & 15, ql = l >> 4;
  const int aoff = (wr * 128 + rl) * 64;
  const int boff = (wc * 64 + rl) * 64;
  const int cs0 = ((ql) ^ (l & 7)) << 3;
  const int cs1 = ((4 + ql) ^ (l & 7)) << 3;

  f32x4 acc[8][4];
  const f32x4 zero = {0.f, 0.f, 0.f, 0.f};
#pragma unroll
  for (int i = 0; i < 8; ++i)
#pragma unroll
    for (int j = 0; j < 4; ++j) acc[i][j] = zero;

  ushortT* Ac = Ab0; ushortT* An = Ab1;
  ushortT* Bc = Bb0; ushortT* Bn = Bb1;

  // prologue: tile0 fully (8 items), tile1 A0,A1,B0 (6 items)
  STAGE_A(Ac, 0, 0); STAGE_A(Ac, 1, 0); STAGE_B(Bc, 0, 0); STAGE_B(Bc, 1, 0);
  STAGE_A(An, 0, 1); STAGE_A(An, 1, 1); STAGE_B(Bn, 0, 1);
  VMC(6);
  BAR;

  short8 Af[4][2];
  short8 Bf[2][2][2];

  for (int t = 0; t < NT; ++t) {
    // ---- phase 0: Q(0,0) ----
#pragma unroll
    for (int m = 0; m < 4; ++m) {
      Af[m][0] = *(const short8*)(Ac + aoff + m * 1024 + cs0);
      Af[m][1] = *(const short8*)(Ac + aoff + m * 1024 + cs1);
    }
#pragma unroll
    for (int n = 0; n < 2; ++n) {
      Bf[0][n][0] = *(const short8*)(Bc + boff + n * 1024 + cs0);
      Bf[0][n][1] = *(const short8*)(Bc + boff + n * 1024 + cs1);
    }
    if (t + 1 < NT) STAGE_B(Bn, 1, t + 1);
    LGKM0; BAR;
    __builtin_amdgcn_s_setprio(1);
    MFMA_PHASE(0, 0);
    __builtin_amdgcn_s_setprio(0);
    BAR;
    // ---- phase 1: Q(0,1) ----
#pragma unroll
    for (int n = 0; n < 2; ++n) {
      Bf[1][n][0] = *(const short8*)(Bc + boff + (2 + n) * 1024 + cs0);
      Bf[1][n][1] = *(const short8*)(Bc + boff + (2 + n) * 1024 + cs1);
    }
    LGKM0; BAR;
    __builtin_amdgcn_s_setprio(1);
    MFMA_PHASE(0, 1);
    __builtin_amdgcn_s_setprio(0);
    BAR;
    // ---- phase 2: Q(1,0) ----
#pragma unroll
    for (int m = 0; m < 4; ++m) {
      Af[m][0] = *(const short8*)(Ac + aoff + (4 + m) * 1024 + cs0);
      Af[m][1] = *(const short8*)(Ac + aoff + (4 + m) * 1024 + cs1);
    }
    LGKM0; BAR;
    __builtin_amdgcn_s_setprio(1);
    MFMA_PHASE(1, 0);
    __builtin_amdgcn_s_setprio(0);
    BAR;
    // ---- phase 3: Q(1,1) ----
    __builtin_amdgcn_s_setprio(1);
    MFMA_PHASE(1, 1);
    __builtin_amdgcn_s_setprio(0);
    BAR;
    // ---- boundary: retire buf cur, prefetch tile t+2 heads, ensure tile t+1 resident ----
    if (t + 2 < NT) {
      STAGE_A(Ac, 0, t + 2); STAGE_A(Ac, 1, t + 2); STAGE_B(Bc, 0, t + 2);
      VMC(6);
    } else if (t + 1 < NT) {
      VMC(0);
    }
    BAR;
    ushortT* tp;
    tp = Ac; Ac = An; An = tp;
    tp = Bc; Bc = Bn; Bn = tp;
  }

  // ---- epilogue ----
#pragma unroll
  for (int m = 0; m < 8; ++m) {
#pragma unroll
    for (int n = 0; n < 4; ++n) {
      const int col = n0 + wc * 64 + n * 16 + rl;
      const float bb = bias[col];
#pragma unroll
      for (int i = 0; i < 4; ++i) {
        const size_t row = (size_t)(m0 + wr * 128 + m * 16 + ql * 4 + i);
        float v = acc[m][n][i] + bb;
        if constexpr (EPI == 1) v += resf[row * (size_t)N + col];
        if constexpr (EPI == 2) v = 0.5f * v * (1.f + erff(v * 0.70710678118654752f));
        if constexpr (EPI == 3) {
          v += bf2f(resb[row * (size_t)N + col]);
          outf[row * (size_t)N + col] = v;
        } else {
          outb[row * (size_t)N + col] = f2bf(v);
        }
      }
    }
  }
}

// ---------------- windowed attention (one block/window, one wave/head) ----------------
__global__ __launch_bounds__(512)
void attn_kernel(const ushortT* __restrict__ qkv, ushortT* __restrict__ out)
{
  __shared__ __align__(16) ushortT sq[8][1544];
  const int wb = blockIdx.x;
  const int b  = wb >> 9;
  const int rr = wb & 511;
  const int w1 = rr >> 6;
  const int g  = rr & 63;
  const int tid = threadIdx.x;

#pragma unroll
  for (int c = 0; c < 3; ++c) {
    const int f = c * 512 + tid;
    const int i = f / 192;
    const int col = (f % 192) * 8;
    const int tin = (64 * g + 8 * i + w1 + 4) & (NSEQ - 1);
    const ushortT* src = qkv + ((size_t)b * NSEQ + tin) * 1536 + col;
    *(short8*)(&sq[i][col]) = *(const short8*)src;
  }
  __syncthreads();

  const int wave = tid >> 6, lane = tid & 63;
  const int h = wave;
  const int qi = lane >> 3, kj = lane & 7;

  float s = 0.f;
  const ushortT* qrow = &sq[qi][h * 64];
  const ushortT* krow = &sq[kj][512 + h * 64];
#pragma unroll
  for (int c = 0; c < 8; ++c) {
    short8 qa = *(const short8*)(qrow + c * 8);
    short8 ka = *(const short8*)(krow + c * 8);
#pragma unroll
    for (int j = 0; j < 8; ++j) s += bf2f((ushortT)qa[j]) * bf2f((ushortT)ka[j]);
  }
  s *= 0.125f;

  const int pq = 64 * g + 8 * qi + w1;
  const int pk = 64 * g + 8 * kj + w1;
  const int cq = (pq < 4088) ? 0 : (pq < 4092 ? 1 : 2);
  const int ck = (pk < 4088) ? 0 : (pk < 4092 ? 1 : 2);
  if (cq != ck) s -= 100.f;

  float mx = s;
  mx = fmaxf(mx, __shfl_xor(mx, 1, 64));
  mx = fmaxf(mx, __shfl_xor(mx, 2, 64));
  mx = fmaxf(mx, __shfl_xor(mx, 4, 64));
  const float e = expf(s - mx);
  float sum = e;
  sum += __shfl_xor(sum, 1, 64);
  sum += __shfl_xor(sum, 2, 64);
  sum += __shfl_xor(sum, 4, 64);
  const float p = e / sum;

  const int dc = lane & 7;
  float o[8];
#pragma unroll
  for (int j = 0; j < 8; ++j) o[j] = 0.f;
#pragma unroll
  for (int k2 = 0; k2 < 8; ++k2) {
    const float pk2 = __shfl(p, (lane & ~7) + k2, 64);
    short8 va = *(const short8*)(&sq[k2][1024 + h * 64 + dc * 8]);
#pragma unroll
    for (int j = 0; j < 8; ++j) o[j] += pk2 * bf2f((ushortT)va[j]);
  }

  const int tout = (512 * qi + 64 * w1 + g + 4) & (NSEQ - 1);
  short8 ov;
#pragma unroll
  for (int j = 0; j < 8; ++j) ov[j] = (short)f2bf(o[j]);
  *(short8*)(out + ((size_t)b * NSEQ + tout) * DIM + h * 64 + dc * 8) = ov;
}

// ---------------- host ----------------
extern "C" void kernel_launch(void* const* d_in, const int* in_sizes, int n_in,
                              void* d_out, int out_size, void* d_ws, size_t ws_size,
                              hipStream_t stream) {
  const float* x      = (const float*)d_in[0];
  const float* n1g    = (const float*)d_in[1];
  const float* n1b    = (const float*)d_in[2];
  const float* qkv_w  = (const float*)d_in[3];
  const float* qkv_b  = (const float*)d_in[4];
  const float* proj_w = (const float*)d_in[5];
  const float* proj_b = (const float*)d_in[6];
  const float* n2g    = (const float*)d_in[7];
  const float* n2b    = (const float*)d_in[8];
  const float* fc1_w  = (const float*)d_in[9];
  const float* fc1_b  = (const float*)d_in[10];
  const float* fc2_w  = (const float*)d_in[11];
  const float* fc2_b  = (const float*)d_in[12];
  float* out = (float*)d_out;

  size_t off = 0;
  char* ws = (char*)d_ws;
  auto alloc = [&](size_t b) { void* p = ws + off; off += (b + 255) & ~(size_t)255; return p; };

  ushortT* qkvw_b = (ushortT*)alloc((size_t)1536 * 512 * 2);
  ushortT* projw_b = (ushortT*)alloc((size_t)512 * 512 * 2);
  ushortT* fc1w_b = (ushortT*)alloc((size_t)2048 * 512 * 2);
  ushortT* fc2w_b = (ushortT*)alloc((size_t)512 * 2048 * 2);
  ushortT* bufA = (ushortT*)alloc((size_t)TOK * 512 * 2);    // xn -> attnout -> h_in
  ushortT* bufQ = (ushortT*)alloc((size_t)TOK * 1536 * 2);   // qkv ; then x1 (bf16)
  ushortT* x1 = bufQ;

  int nch = 1;
  while (nch < 16) {
    size_t need = (size_t)(TOK / nch) * 2048 * 2;
    if (off + need <= ws_size) break;
    nch <<= 1;
  }
  ushortT* h1 = (ushortT*)(ws + off);

  cvt_kernel<<<(1536 * 512 / 4 + 255) / 256, 256, 0, stream>>>(qkv_w, qkvw_b, 1536 * 512 / 4);
  cvt_kernel<<<(512 * 512 / 4 + 255) / 256, 256, 0, stream>>>(proj_w, projw_b, 512 * 512 / 4);
  cvt_kernel<<<(2048 * 512 / 4 + 255) / 256, 256, 0, stream>>>(fc1_w, fc1w_b, 2048 * 512 / 4);
  cvt_kernel<<<(512 * 2048 / 4 + 255) / 256, 256, 0, stream>>>(fc2_w, fc2w_b, 512 * 2048 / 4);

  ln_kernel<false><<<TOK / 4, 256, 0, stream>>>(x, n1g, n1b, bufA);

  gemm256<0><<<dim3(TOK / 256, 1536 / 256), 512, 0, stream>>>(
      bufA, qkvw_b, qkv_b, TOK, 1536, 512, bufQ, nullptr, nullptr, nullptr);

  attn_kernel<<<8192, 512, 0, stream>>>(bufQ, bufA);

  gemm256<1><<<dim3(TOK / 256, 512 / 256), 512, 0, stream>>>(
      bufA, projw_b, proj_b, TOK, 512, 512, x1, nullptr, x, nullptr);

  ln_kernel<true><<<TOK / 4, 256, 0, stream>>>(x1, n2g, n2b, bufA);

  const int tc = TOK / nch;
  for (int c = 0; c < nch; ++c) {
    const ushortT* hin = bufA + (size_t)c * tc * 512;
    gemm256<2><<<dim3(tc / 256, 2048 / 256), 512, 0, stream>>>(
        hin, fc1w_b, fc1_b, tc, 2048, 512, h1, nullptr, nullptr, nullptr);
    gemm256<3><<<dim3(tc / 256, 512 / 256), 512, 0, stream>>>(
        h1, fc2w_b, fc2_b, tc, 512, 2048, nullptr, out + (size_t)c * tc * 512,
        nullptr, x1 + (size_t)c * tc * 512);
  }
}

// Round 3
// 699.992 us; speedup vs baseline: 1.3237x; 1.1910x over previous
//
#include <hip/hip_runtime.h>
#include <hip/hip_bf16.h>
#include <math.h>

typedef unsigned short ushortT;
typedef __attribute__((ext_vector_type(8))) short short8;
typedef __attribute__((ext_vector_type(4))) short short4v;
typedef __attribute__((ext_vector_type(4))) float f32x4;
typedef __attribute__((ext_vector_type(4))) float float4v;

#define TOK 65536
#define NSEQ 4096
#define DIM 512

__device__ __forceinline__ float bf2f(ushortT u) {
  union { float f; unsigned int i; } v; v.i = ((unsigned int)u) << 16; return v.f;
}
__device__ __forceinline__ ushortT f2bf(float f) {
  union { float f; unsigned int i; } v; v.f = f;
  unsigned int r = v.i + 0x7fffu + ((v.i >> 16) & 1u);
  return (ushortT)(r >> 16);
}

// exact-grade GELU via A&S 7.1.26 erf (|err| ~1e-6), ~13 VALU ops vs erff's ~25
__device__ __forceinline__ float fast_gelu(float x) {
  const float y = fabsf(x) * 0.70710678118654752f;
  const float t = __builtin_amdgcn_rcpf(__builtin_fmaf(0.3275911f, y, 1.f));
  float p = 1.061405429f;
  p = __builtin_fmaf(p, t, -1.453152027f);
  p = __builtin_fmaf(p, t, 1.421413741f);
  p = __builtin_fmaf(p, t, -0.284496736f);
  p = __builtin_fmaf(p, t, 0.254829592f);
  p = p * t;
  const float e = __builtin_amdgcn_exp2f(-y * y * 1.4426950408889634f);
  float erfv = __builtin_fmaf(-p, e, 1.f);
  erfv = copysignf(erfv, x);
  return 0.5f * x * (1.f + erfv);
}

#define GLOAD_LDS(gp, lp) __builtin_amdgcn_global_load_lds( \
    (const __attribute__((address_space(1))) unsigned int*)(gp), \
    (__attribute__((address_space(3))) unsigned int*)(lp), 16, 0, 0)

#define LGKM0 do { asm volatile("s_waitcnt lgkmcnt(0)" ::: "memory"); \
                   __builtin_amdgcn_sched_barrier(0); } while (0)
#define BAR __builtin_amdgcn_s_barrier()
#define VMC(n) asm volatile("s_waitcnt vmcnt(" #n ")" ::: "memory")
#define SB0 __builtin_amdgcn_sched_barrier(0)

// ---------------- weight f32 -> bf16 convert ----------------
__global__ void cvt_kernel(const float* __restrict__ in, ushortT* __restrict__ out, int n4) {
  int i = blockIdx.x * 256 + threadIdx.x;
  if (i >= n4) return;
  float4v v = *(const float4v*)(in + (size_t)i * 4);
  short4v o;
#pragma unroll
  for (int j = 0; j < 4; ++j) o[j] = (short)f2bf(v[j]);
  *(short4v*)(out + (size_t)i * 4) = o;
}

// ---------------- LayerNorm (one wave per token) ----------------
template <bool INBF>
__global__ __launch_bounds__(256)
void ln_kernel(const void* __restrict__ inp, const float* __restrict__ gw,
               const float* __restrict__ bw, ushortT* __restrict__ out)
{
  const int lane = threadIdx.x & 63;
  const size_t tok = (size_t)blockIdx.x * 4 + (threadIdx.x >> 6);
  const int col = lane * 8;
  float x[8];
  if constexpr (INBF) {
    short8 v = *(const short8*)((const ushortT*)inp + tok * DIM + col);
#pragma unroll
    for (int j = 0; j < 8; ++j) x[j] = bf2f((ushortT)v[j]);
  } else {
    const float* p = (const float*)inp + tok * DIM + col;
    float4v a = *(const float4v*)p, b = *(const float4v*)(p + 4);
#pragma unroll
    for (int j = 0; j < 4; ++j) { x[j] = a[j]; x[4 + j] = b[j]; }
  }
  float s = 0.f, ss = 0.f;
#pragma unroll
  for (int j = 0; j < 8; ++j) { s += x[j]; ss += x[j] * x[j]; }
#pragma unroll
  for (int off = 1; off < 64; off <<= 1) {
    s += __shfl_xor(s, off, 64);
    ss += __shfl_xor(ss, off, 64);
  }
  const float mean = s * (1.f / 512.f);
  const float var = ss * (1.f / 512.f) - mean * mean;
  const float rstd = rsqrtf(var + 1e-5f);
  float4v g1 = *(const float4v*)(gw + col), g2 = *(const float4v*)(gw + col + 4);
  float4v b1 = *(const float4v*)(bw + col), b2 = *(const float4v*)(bw + col + 4);
  short8 o;
#pragma unroll
  for (int j = 0; j < 4; ++j) {
    o[j]     = (short)f2bf((x[j]     - mean) * rstd * g1[j] + b1[j]);
    o[4 + j] = (short)f2bf((x[4 + j] - mean) * rstd * g2[j] + b2[j]);
  }
  *(short8*)(out + tok * DIM + col) = o;
}

// ---------------- 256x256 8-phase GEMM: C = A(M,K) * Bt(N,K)^T + bias ----------------
// EPI 0: out bf16 (QKV) | 1: bf16 +f32 residual (proj) | 2: bf16 GELU (fc1) | 3: f32 +bf16 residual (fc2)
#define MFMA_PHASE(MQ, NQ) \
  _Pragma("unroll") \
  for (int s_ = 0; s_ < 2; ++s_) \
    _Pragma("unroll") \
    for (int m_ = 0; m_ < 4; ++m_) \
      _Pragma("unroll") \
      for (int n_ = 0; n_ < 2; ++n_) \
        acc[(MQ) * 4 + m_][(NQ) * 2 + n_] = __builtin_amdgcn_mfma_f32_16x16x32_bf16( \
            Af[m_][s_], Bf[NQ][n_][s_], acc[(MQ) * 4 + m_][(NQ) * 2 + n_], 0, 0, 0)

#define STAGE_A(bufp, h, kt) do { \
    GLOAD_LDS(gA + (size_t)((h) * 128) * K + (size_t)(kt) * 64,     (bufp) + (h) * 8192 + w * 1024); \
    GLOAD_LDS(gA + (size_t)((h) * 128 + 8) * K + (size_t)(kt) * 64, (bufp) + (h) * 8192 + w * 1024 + 512); \
  } while (0)
#define STAGE_B(bufp, h, kt) do { \
    GLOAD_LDS(gB + (size_t)((h) * 128) * K + (size_t)(kt) * 64,     (bufp) + (h) * 8192 + w * 1024); \
    GLOAD_LDS(gB + (size_t)((h) * 128 + 8) * K + (size_t)(kt) * 64, (bufp) + (h) * 8192 + w * 1024 + 512); \
  } while (0)

template <int EPI>
__global__ __launch_bounds__(512, 2)
void gemm256(const ushortT* __restrict__ A, const ushortT* __restrict__ Bt,
             const float* __restrict__ bias, int M, int N, int K,
             ushortT* __restrict__ outb, float* __restrict__ outf,
             const float* __restrict__ resf, const ushortT* __restrict__ resb)
{
  __shared__ __align__(16) ushortT sm[65536];   // 128 KiB
  ushortT* const Ab0 = sm;
  ushortT* const Ab1 = sm + 16384;
  ushortT* const Bb0 = sm + 32768;
  ushortT* const Bb1 = sm + 49152;

  const int tid = threadIdx.x;
  const int w = tid >> 6, l = tid & 63;
  const int wr = w >> 2, wc = w & 3;

  // XCD-bijective swizzle; consecutive swizzled ids share the A panel (same mb)
  const int nwg = gridDim.x * gridDim.y;
  int wg = blockIdx.y * gridDim.x + blockIdx.x;
  {
    const int q = nwg >> 3, r8 = nwg & 7;
    const int xc = wg & 7, yc = wg >> 3;
    wg = (xc < r8 ? xc * (q + 1) : r8 * (q + 1) + (xc - r8) * q) + yc;
  }
  const int nbn = N >> 8;
  const int mb = wg / nbn, nb = wg % nbn;
  const int m0 = mb << 8, n0 = nb << 8;
  const int NT = K >> 6;

  // staging source (per-lane, inverse-swizzled chunk)
  const ushortT* gA = A  + (size_t)(m0 + w * 16 + (l >> 3)) * K + (((l & 7) ^ (l >> 3)) << 3);
  const ushortT* gB = Bt + (size_t)(n0 + w * 16 + (l >> 3)) * K + (((l & 7) ^ (l >> 3)) << 3);

  // ds_read addressing (swizzled)
  const int rl = l & 15, ql = l >> 4;
  const int aoff = (wr * 128 + rl) * 64;
  const int boff = (wc * 64 + rl) * 64;
  const int cs0 = ((ql) ^ (l & 7)) << 3;
  const int cs1 = ((4 + ql) ^ (l & 7)) << 3;

  f32x4 acc[8][4];
  const f32x4 zero = {0.f, 0.f, 0.f, 0.f};
#pragma unroll
  for (int i = 0; i < 8; ++i)
#pragma unroll
    for (int j = 0; j < 4; ++j) acc[i][j] = zero;

  ushortT* Ac = Ab0; ushortT* An = Ab1;
  ushortT* Bc = Bb0; ushortT* Bn = Bb1;

  // prologue: tile0 fully (8 loads), tile1 A0,A1,B0 (6 loads)
  STAGE_A(Ac, 0, 0); STAGE_A(Ac, 1, 0); STAGE_B(Bc, 0, 0); STAGE_B(Bc, 1, 0);
  STAGE_A(An, 0, 1); STAGE_A(An, 1, 1); STAGE_B(Bn, 0, 1);
  VMC(6);
  BAR;

  short8 Af[4][2];
  short8 Bf[2][2][2];

  for (int t = 0; t < NT; ++t) {
    // ---- phase 0: Q(0,0) ----
#pragma unroll
    for (int m = 0; m < 4; ++m) {
      Af[m][0] = *(const short8*)(Ac + aoff + m * 1024 + cs0);
      Af[m][1] = *(const short8*)(Ac + aoff + m * 1024 + cs1);
    }
#pragma unroll
    for (int n = 0; n < 2; ++n) {
      Bf[0][n][0] = *(const short8*)(Bc + boff + n * 1024 + cs0);
      Bf[0][n][1] = *(const short8*)(Bc + boff + n * 1024 + cs1);
    }
    if (t + 1 < NT) STAGE_B(Bn, 1, t + 1);
    SB0;
    BAR; LGKM0;
    __builtin_amdgcn_s_setprio(1);
    MFMA_PHASE(0, 0);
    __builtin_amdgcn_s_setprio(0);
    BAR;
    // ---- phase 1: Q(0,1) ----
#pragma unroll
    for (int n = 0; n < 2; ++n) {
      Bf[1][n][0] = *(const short8*)(Bc + boff + (2 + n) * 1024 + cs0);
      Bf[1][n][1] = *(const short8*)(Bc + boff + (2 + n) * 1024 + cs1);
    }
    SB0;
    BAR; LGKM0;
    __builtin_amdgcn_s_setprio(1);
    MFMA_PHASE(0, 1);
    __builtin_amdgcn_s_setprio(0);
    BAR;
    // ---- phase 2: Q(1,0) ----
#pragma unroll
    for (int m = 0; m < 4; ++m) {
      Af[m][0] = *(const short8*)(Ac + aoff + (4 + m) * 1024 + cs0);
      Af[m][1] = *(const short8*)(Ac + aoff + (4 + m) * 1024 + cs1);
    }
    SB0;
    BAR; LGKM0;
    __builtin_amdgcn_s_setprio(1);
    MFMA_PHASE(1, 0);
    __builtin_amdgcn_s_setprio(0);
    BAR;
    SB0;   // pin: ph3's LDS writes must not hoist above this barrier
    // ---- phase 3: Q(1,1) + merged boundary ----
    // all tile-t ds_reads completed chip-wide at ph2's post-barrier, so
    // staging tile t+2 into Ac/Bc is race-free; vmcnt(6) forces tile t+1
    // residency (everything older than the 6 loads just issued).
    if (t + 2 < NT) {
      STAGE_A(Ac, 0, t + 2); STAGE_A(Ac, 1, t + 2); STAGE_B(Bc, 0, t + 2);
      VMC(6);
    } else if (t + 1 < NT) {
      VMC(0);
    }
    __builtin_amdgcn_s_setprio(1);
    MFMA_PHASE(1, 1);
    __builtin_amdgcn_s_setprio(0);
    BAR;
    ushortT* tp;
    tp = Ac; Ac = An; An = tp;
    tp = Bc; Bc = Bn; Bn = tp;
  }

  // ---- epilogue ----
#pragma unroll
  for (int m = 0; m < 8; ++m) {
#pragma unroll
    for (int n = 0; n < 4; ++n) {
      const int col = n0 + wc * 64 + n * 16 + rl;
      const float bb = bias[col];
#pragma unroll
      for (int i = 0; i < 4; ++i) {
        const size_t row = (size_t)(m0 + wr * 128 + m * 16 + ql * 4 + i);
        float v = acc[m][n][i] + bb;
        if constexpr (EPI == 1) v += resf[row * (size_t)N + col];
        if constexpr (EPI == 2) v = fast_gelu(v);
        if constexpr (EPI == 3) {
          v += bf2f(resb[row * (size_t)N + col]);
          outf[row * (size_t)N + col] = v;
        } else {
          outb[row * (size_t)N + col] = f2bf(v);
        }
      }
    }
  }
}

// ---------------- windowed attention (one block/window, one wave/head) ----------------
__global__ __launch_bounds__(512)
void attn_kernel(const ushortT* __restrict__ qkv, ushortT* __restrict__ out)
{
  __shared__ __align__(16) ushortT sq[8][1544];
  const int wb = blockIdx.x;
  const int b  = wb >> 9;
  const int rr = wb & 511;
  const int w1 = rr >> 6;
  const int g  = rr & 63;
  const int tid = threadIdx.x;

#pragma unroll
  for (int c = 0; c < 3; ++c) {
    const int f = c * 512 + tid;
    const int i = f / 192;
    const int col = (f % 192) * 8;
    const int tin = (64 * g + 8 * i + w1 + 4) & (NSEQ - 1);
    const ushortT* src = qkv + ((size_t)b * NSEQ + tin) * 1536 + col;
    *(short8*)(&sq[i][col]) = *(const short8*)src;
  }
  __syncthreads();

  const int wave = tid >> 6, lane = tid & 63;
  const int h = wave;
  const int qi = lane >> 3, kj = lane & 7;

  float s = 0.f;
  const ushortT* qrow = &sq[qi][h * 64];
  const ushortT* krow = &sq[kj][512 + h * 64];
#pragma unroll
  for (int c = 0; c < 8; ++c) {
    short8 qa = *(const short8*)(qrow + c * 8);
    short8 ka = *(const short8*)(krow + c * 8);
#pragma unroll
    for (int j = 0; j < 8; ++j) s += bf2f((ushortT)qa[j]) * bf2f((ushortT)ka[j]);
  }
  s *= 0.125f;

  const int pq = 64 * g + 8 * qi + w1;
  const int pk = 64 * g + 8 * kj + w1;
  const int cq = (pq < 4088) ? 0 : (pq < 4092 ? 1 : 2);
  const int ck = (pk < 4088) ? 0 : (pk < 4092 ? 1 : 2);
  if (cq != ck) s -= 100.f;

  float mx = s;
  mx = fmaxf(mx, __shfl_xor(mx, 1, 64));
  mx = fmaxf(mx, __shfl_xor(mx, 2, 64));
  mx = fmaxf(mx, __shfl_xor(mx, 4, 64));
  const float e = expf(s - mx);
  float sum = e;
  sum += __shfl_xor(sum, 1, 64);
  sum += __shfl_xor(sum, 2, 64);
  sum += __shfl_xor(sum, 4, 64);
  const float p = e / sum;

  const int dc = lane & 7;
  float o[8];
#pragma unroll
  for (int j = 0; j < 8; ++j) o[j] = 0.f;
#pragma unroll
  for (int k2 = 0; k2 < 8; ++k2) {
    const float pk2 = __shfl(p, (lane & ~7) + k2, 64);
    short8 va = *(const short8*)(&sq[k2][1024 + h * 64 + dc * 8]);
#pragma unroll
    for (int j = 0; j < 8; ++j) o[j] += pk2 * bf2f((ushortT)va[j]);
  }

  const int tout = (512 * qi + 64 * w1 + g + 4) & (NSEQ - 1);
  short8 ov;
#pragma unroll
  for (int j = 0; j < 8; ++j) ov[j] = (short)f2bf(o[j]);
  *(short8*)(out + ((size_t)b * NSEQ + tout) * DIM + h * 64 + dc * 8) = ov;
}

// ---------------- host ----------------
extern "C" void kernel_launch(void* const* d_in, const int* in_sizes, int n_in,
                              void* d_out, int out_size, void* d_ws, size_t ws_size,
                              hipStream_t stream) {
  const float* x      = (const float*)d_in[0];
  const float* n1g    = (const float*)d_in[1];
  const float* n1b    = (const float*)d_in[2];
  const float* qkv_w  = (const float*)d_in[3];
  const float* qkv_b  = (const float*)d_in[4];
  const float* proj_w = (const float*)d_in[5];
  const float* proj_b = (const float*)d_in[6];
  const float* n2g    = (const float*)d_in[7];
  const float* n2b    = (const float*)d_in[8];
  const float* fc1_w  = (const float*)d_in[9];
  const float* fc1_b  = (const float*)d_in[10];
  const float* fc2_w  = (const float*)d_in[11];
  const float* fc2_b  = (const float*)d_in[12];
  float* out = (float*)d_out;

  size_t off = 0;
  char* ws = (char*)d_ws;
  auto alloc = [&](size_t b) { void* p = ws + off; off += (b + 255) & ~(size_t)255; return p; };

  ushortT* qkvw_b = (ushortT*)alloc((size_t)1536 * 512 * 2);
  ushortT* projw_b = (ushortT*)alloc((size_t)512 * 512 * 2);
  ushortT* fc1w_b = (ushortT*)alloc((size_t)2048 * 512 * 2);
  ushortT* fc2w_b = (ushortT*)alloc((size_t)512 * 2048 * 2);
  ushortT* bufA = (ushortT*)alloc((size_t)TOK * 512 * 2);    // xn -> attnout -> h_in
  ushortT* bufQ = (ushortT*)alloc((size_t)TOK * 1536 * 2);   // qkv ; then x1 (bf16)
  ushortT* x1 = bufQ;

  int nch = 1;
  while (nch < 16) {
    size_t need = (size_t)(TOK / nch) * 2048 * 2;
    if (off + need <= ws_size) break;
    nch <<= 1;
  }
  ushortT* h1 = (ushortT*)(ws + off);

  cvt_kernel<<<(1536 * 512 / 4 + 255) / 256, 256, 0, stream>>>(qkv_w, qkvw_b, 1536 * 512 / 4);
  cvt_kernel<<<(512 * 512 / 4 + 255) / 256, 256, 0, stream>>>(proj_w, projw_b, 512 * 512 / 4);
  cvt_kernel<<<(2048 * 512 / 4 + 255) / 256, 256, 0, stream>>>(fc1_w, fc1w_b, 2048 * 512 / 4);
  cvt_kernel<<<(512 * 2048 / 4 + 255) / 256, 256, 0, stream>>>(fc2_w, fc2w_b, 512 * 2048 / 4);

  ln_kernel<false><<<TOK / 4, 256, 0, stream>>>(x, n1g, n1b, bufA);

  gemm256<0><<<dim3(TOK / 256, 1536 / 256), 512, 0, stream>>>(
      bufA, qkvw_b, qkv_b, TOK, 1536, 512, bufQ, nullptr, nullptr, nullptr);

  attn_kernel<<<8192, 512, 0, stream>>>(bufQ, bufA);

  gemm256<1><<<dim3(TOK / 256, 512 / 256), 512, 0, stream>>>(
      bufA, projw_b, proj_b, TOK, 512, 512, x1, nullptr, x, nullptr);

  ln_kernel<true><<<TOK / 4, 256, 0, stream>>>(x1, n2g, n2b, bufA);

  const int tc = TOK / nch;
  for (int c = 0; c < nch; ++c) {
    const ushortT* hin = bufA + (size_t)c * tc * 512;
    gemm256<2><<<dim3(tc / 256, 2048 / 256), 512, 0, stream>>>(
        hin, fc1w_b, fc1_b, tc, 2048, 512, h1, nullptr, nullptr, nullptr);
    gemm256<3><<<dim3(tc / 256, 512 / 256), 512, 0, stream>>>(
        h1, fc2w_b, fc2_b, tc, 512, 2048, nullptr, out + (size_t)c * tc * 512,
        nullptr, x1 + (size_t)c * tc * 512);
  }
}